// Round 5
// baseline (382.809 us; speedup 1.0000x reference)
//
#include <hip/hip_runtime.h>

typedef _Float16 half_t;
typedef __attribute__((ext_vector_type(8))) _Float16 half8;
typedef __attribute__((ext_vector_type(4))) _Float16 half4;
typedef __attribute__((ext_vector_type(4))) float f32x4;

#define B_ 4
#define N_ 4096
#define D_ 1024
#define R_ (B_ * N_) // 16384

// ---------------------------------------------------------------------------
// async global->LDS, 16B per lane. LDS dest must be wave-uniform base + lane*16.
__device__ __forceinline__ void gload_lds16(const half_t* g, half_t* l) {
    __builtin_amdgcn_global_load_lds(
        (const __attribute__((address_space(1))) unsigned int*)g,
        (__attribute__((address_space(3))) unsigned int*)l, 16, 0, 0);
}

// raw workgroup barrier (no implicit vmcnt/lgkmcnt drain; explicit counted
// vmcnt before it carries gload_lds->LDS visibility across waves).
__device__ __forceinline__ void wgbar() {
    asm volatile("" ::: "memory");
    __builtin_amdgcn_s_barrier();
    asm volatile("" ::: "memory");
}

// ---------------------------------------------------------------------------
// CO-RESIDENT GEMM engine: C[m,n] = sum_k A[m,k] * Bt[n,k]
// 128x256 tile, BK=32, 512 threads (8 waves = 2M x 4N, each 64x64 output).
// LDS = 48 KiB (A 16K + B 32K, double-buffered) and acc[4][4] (~64 VGPR +
// frags) with __launch_bounds__(512,4) -> VGPR<=128 -> TWO blocks per CU.
// Rationale (R4 counters): at 1 block/CU the per-block prologue fill (~11k cyc)
// and epilogue store drain (~25k cyc) are fully exposed (MfmaUtil 35%).
// A co-resident block's K-loop hides them via HW wave co-scheduling (m114);
// the single-prefetch vmcnt(0) drain per tile is likewise covered by the
// other block. Per tile: { stage kt+1 (3 gloads) | 8x ds_read_b128 |
// 16 MFMA (setprio) | vmcnt(0) barrier }.
// LDS rows [.][32] halfs (64B rows), 16B chunks XOR-swizzled both sides:
//   phys_chunk(row,q) = row*4 + (q ^ ((row>>1)&3))
// EPI: 0 = fp32 C, 1 = f16 C, 2 = fp32 C + bias (bias indexed by column)
// ZSHIFT: blockIdx.z = (batch << ZSHIFT) | ksplit; k window = ksplit*K .. +K.
// Requires: K % 32 == 0, nk = K/32 >= 2.
template <int EPI, int ZSHIFT, int SWAP>
__global__ __launch_bounds__(512, 4) void gemmco(
    const half_t* __restrict__ A, const half_t* __restrict__ Bt,
    void* __restrict__ Cv, const float* __restrict__ bias,
    int lda, int ldb, int ldc, int K,
    long sA, long sB, long sC, float scale)
{
    __shared__ __align__(16) half_t As[2][128 * 32]; // 16 KiB
    __shared__ __align__(16) half_t Bs[2][256 * 32]; // 32 KiB

    const int t = threadIdx.x;
    const int wave = t >> 6;
    const int lane = t & 63;
    const int l15 = lane & 15;
    const int q = lane >> 4;
    const int wm = wave >> 2;  // 0..1 (64-row band)
    const int wn = wave & 3;   // 0..3 (64-col band)
    const int m0 = (SWAP ? blockIdx.x : blockIdx.y) * 128;
    const int n0 = (SWAP ? blockIdx.y : blockIdx.x) * 256;
    const long zb = blockIdx.z >> ZSHIFT;
    const int zs = blockIdx.z & ((1 << ZSHIFT) - 1);

    // staging: physical chunk c holds logical (row = c>>2, chunk = (c&3)^((c>>3)&3))
    const int c0 = t, c1 = t + 512;
    const int gA = ((c0 & 3) ^ ((c0 >> 3) & 3)) * 8; // halfs
    const int gB1 = ((c1 & 3) ^ ((c1 >> 3) & 3)) * 8;
    const int rA = c0 >> 2;        // 0..127 (A rows; also B rows 0..127)
    const int rB1 = c1 >> 2;       // 128..255

    const half_t* Ab = A + zb * sA + (long)m0 * lda + zs * K;
    const half_t* Bb = Bt + zb * sB + (long)n0 * ldb + zs * K;
    const long a0 = (long)rA * lda + gA;
    const long b0 = (long)rA * ldb + gA;
    const long b1 = (long)rB1 * ldb + gB1;

    // fragment ds_read: row bits 1..2 feed the chunk XOR
    const int qq = (q ^ ((l15 >> 1) & 3)) * 8; // halfs

    f32x4 acc[4][4] = {};
    const int nk = K >> 5;

#define STAGE(kt) do { const int kb_ = (kt) * 32; const int bf_ = (kt) & 1; \
        gload_lds16(Ab + a0 + kb_, &As[bf_][c0 * 8]);                       \
        gload_lds16(Bb + b0 + kb_, &Bs[bf_][c0 * 8]);                       \
        gload_lds16(Bb + b1 + kb_, &Bs[bf_][c1 * 8]); } while (0)

    STAGE(0);
    asm volatile("s_waitcnt vmcnt(0)" ::: "memory");
    wgbar();

    for (int kt = 0; kt < nk; ++kt) {
        const int cur = kt & 1;
        if (kt + 1 < nk) STAGE(kt + 1); // -> other buffer; its readers passed
                                        //    the barrier at end of kt-1
        half8 af[4], bf[4];
#pragma unroll
        for (int j = 0; j < 4; j++)
            bf[j] = *(const half8*)&Bs[cur][(wn * 64 + j * 16 + l15) * 32 + qq];
#pragma unroll
        for (int i = 0; i < 4; i++)
            af[i] = *(const half8*)&As[cur][(wm * 64 + i * 16 + l15) * 32 + qq];
        __builtin_amdgcn_s_setprio(1);
#pragma unroll
        for (int i = 0; i < 4; i++)
#pragma unroll
            for (int j = 0; j < 4; j++)
                acc[i][j] = __builtin_amdgcn_mfma_f32_16x16x32_f16(af[i], bf[j], acc[i][j], 0, 0, 0);
        __builtin_amdgcn_s_setprio(0);
        if (kt + 1 < nk) {
            // own stage loads done -> after barrier, all waves' loads visible
            asm volatile("s_waitcnt vmcnt(0)" ::: "memory");
            wgbar();
        }
    }
#undef STAGE

    // epilogue: acc[i][j] -> row = wm*64 + i*16 + q*4 + r, col = wn*64 + j*16 + l15
    if (EPI == 1) {
        half_t* C = (half_t*)Cv + (long)blockIdx.z * sC + (long)m0 * ldc + n0;
#pragma unroll
        for (int i = 0; i < 4; i++) {
            const int rowb = wm * 64 + i * 16 + q * 4;
#pragma unroll
            for (int j = 0; j < 4; j++) {
                const int col = wn * 64 + j * 16 + l15;
#pragma unroll
                for (int r = 0; r < 4; r++)
                    C[(long)(rowb + r) * ldc + col] = (half_t)(acc[i][j][r] * scale);
            }
        }
    } else {
        float* C = (float*)Cv + (long)blockIdx.z * sC + (long)m0 * ldc + n0;
#pragma unroll
        for (int i = 0; i < 4; i++) {
            const int rowb = wm * 64 + i * 16 + q * 4;
#pragma unroll
            for (int j = 0; j < 4; j++) {
                const int col = wn * 64 + j * 16 + l15;
                const float bv = (EPI == 2) ? bias[n0 + col] : 0.0f;
#pragma unroll
                for (int r = 0; r < 4; r++)
                    C[(long)(rowb + r) * ldc + col] = acc[i][j][r] * scale + bv;
            }
        }
    }
}

// ---------------------------------------------------------------------------
// sum 4 split-K f16 partials (fp32 math) -> f16. P laid [z = b*4+s][1M halfs].
// Works for any output of size G*1M halfs (grid = G*512 blocks).
__global__ __launch_bounds__(256) void ctx_reduce_h(
    const half_t* __restrict__ P, half_t* __restrict__ ctx)
{
    const long i = ((long)blockIdx.x * 256 + threadIdx.x) * 8;
    const long b = i >> 20;
    const long idx = i & ((1L << 20) - 1);
    const half_t* p = P + (b * 4) * (1L << 20) + idx;
    const half8 s0 = *(const half8*)(p);
    const half8 s1 = *(const half8*)(p + (1L << 20));
    const half8 s2 = *(const half8*)(p + 2 * (1L << 20));
    const half8 s3 = *(const half8*)(p + 3 * (1L << 20));
    half8 o;
#pragma unroll
    for (int j = 0; j < 8; j++)
        o[j] = (half_t)((float)s0[j] + (float)s1[j] + (float)s2[j] + (float)s3[j]);
    *(half8*)(ctx + i) = o;
}

// ---------------------------------------------------------------------------
// Fused preparation, one dispatch, 256-thread blocks:
//   bid <  4096         : transpose 32x32 f32 tile of W{q,k,v,o} -> f16 into Wt
//   4096 <= bid < 4608  : Wv fp32 -> f16 straight copy (Wvh)
//   4608 <= bid < 12800 : x fp32 -> f16 (Xh), 2048 elems per block
__global__ __launch_bounds__(256) void prep_fused(
    const float* __restrict__ x,
    const float* __restrict__ W0, const float* __restrict__ W1,
    const float* __restrict__ W2, const float* __restrict__ W3,
    half_t* __restrict__ Wt, half_t* __restrict__ Wvh, half_t* __restrict__ Xh)
{
    const int bid = blockIdx.x;
    const int t = threadIdx.x;
    if (bid < 4096) {
        __shared__ float tile[32][33];
        const int z = bid >> 10;
        const int rem = bid & 1023;
        const int by = (rem >> 5) * 32, bx = (rem & 31) * 32;
        const float* W = z == 0 ? W0 : z == 1 ? W1 : z == 2 ? W2 : W3;
        half_t* dst = Wt + (size_t)z * 1024 * 1024;
        const int tx = t & 31, ty = t >> 5; // 32 x 8
#pragma unroll
        for (int yy = ty; yy < 32; yy += 8)
            tile[yy][tx] = W[(long)(by + yy) * 1024 + bx + tx];
        __syncthreads();
#pragma unroll
        for (int yy = ty; yy < 32; yy += 8)
            dst[(long)(bx + yy) * 1024 + by + tx] = (half_t)tile[tx][yy];
    } else if (bid < 4608) {
        const long i = ((long)(bid - 4096) * 256 + t) * 8;
        const float4 a = *(const float4*)(W2 + i);
        const float4 b = *(const float4*)(W2 + i + 4);
        half8 o = {(half_t)a.x, (half_t)a.y, (half_t)a.z, (half_t)a.w,
                   (half_t)b.x, (half_t)b.y, (half_t)b.z, (half_t)b.w};
        *(half8*)(Wvh + i) = o;
    } else {
        const long i = ((long)(bid - 4608) * 256 + t) * 8;
        const float4 a = *(const float4*)(x + i);
        const float4 b = *(const float4*)(x + i + 4);
        half8 o = {(half_t)a.x, (half_t)a.y, (half_t)a.z, (half_t)a.w,
                   (half_t)b.x, (half_t)b.y, (half_t)b.z, (half_t)b.w};
        *(half8*)(Xh + i) = o;
    }
}

// ---------------------------------------------------------------------------
// Fused softmax dispatch (both softmaxes, launched after both logits GEMMs):
//   bid < 4096 : sequence softmax over 4096 for row (b,d) of the K-logit part
//                of KVreg [B][2048][4096]; 256 thr, 16 elems/thr; out *64 -> Kt.
//   bid >= 4096: feature softmax over 1024, ONE WAVE PER ROW (4 rows/block),
//                no LDS, no barriers; out *64 -> Qh.
__global__ __launch_bounds__(256) void softmax_fused(
    const half_t* __restrict__ KV, half_t* __restrict__ Kt,
    const half_t* __restrict__ Qlog, half_t* __restrict__ Qh)
{
    const int bid = blockIdx.x;
    const int t = threadIdx.x;
    if (bid < B_ * D_) {
        const long r = bid;
        const long b = r >> 10;
        const long d = r & 1023;
        const half_t* row = KV + (b * 2048 + d) * 4096;
        const half8 h0 = *(const half8*)(row + t * 16);
        const half8 h1 = *(const half8*)(row + t * 16 + 8);
        float v[16];
#pragma unroll
        for (int j = 0; j < 8; j++) { v[j] = (float)h0[j]; v[8 + j] = (float)h1[j]; }
        float m = v[0];
#pragma unroll
        for (int j = 1; j < 16; j++) m = fmaxf(m, v[j]);
#pragma unroll
        for (int o = 32; o > 0; o >>= 1) m = fmaxf(m, __shfl_xor(m, o, 64));
        __shared__ float redm[4], reds[4];
        const int wave = t >> 6;
        if ((t & 63) == 0) redm[wave] = m;
        __syncthreads();
        m = fmaxf(fmaxf(redm[0], redm[1]), fmaxf(redm[2], redm[3]));
        float s = 0.0f;
#pragma unroll
        for (int j = 0; j < 16; j++) { v[j] = __expf(v[j] - m); s += v[j]; }
#pragma unroll
        for (int o = 32; o > 0; o >>= 1) s += __shfl_xor(s, o, 64);
        if ((t & 63) == 0) reds[wave] = s;
        __syncthreads();
        s = reds[0] + reds[1] + reds[2] + reds[3];
        const float rs = 64.0f / s;
        half8 o0, o1;
#pragma unroll
        for (int j = 0; j < 8; j++) {
            o0[j] = (half_t)(v[j] * rs);
            o1[j] = (half_t)(v[8 + j] * rs);
        }
        *(half8*)(Kt + r * 4096 + t * 16) = o0;
        *(half8*)(Kt + r * 4096 + t * 16 + 8) = o1;
    } else {
        const long r = ((long)(bid - B_ * D_)) * 4 + (t >> 6);
        const int lane = t & 63;
        const half_t* row = Qlog + r * 1024 + lane * 16;
        const half8 h0 = *(const half8*)(row);
        const half8 h1 = *(const half8*)(row + 8);
        float v[16];
#pragma unroll
        for (int j = 0; j < 8; j++) { v[j] = (float)h0[j]; v[8 + j] = (float)h1[j]; }
        float m = v[0];
#pragma unroll
        for (int j = 1; j < 16; j++) m = fmaxf(m, v[j]);
#pragma unroll
        for (int o = 32; o > 0; o >>= 1) m = fmaxf(m, __shfl_xor(m, o, 64));
        float s = 0.0f;
#pragma unroll
        for (int j = 0; j < 16; j++) { v[j] = __expf(v[j] - m); s += v[j]; }
#pragma unroll
        for (int o = 32; o > 0; o >>= 1) s += __shfl_xor(s, o, 64);
        const float rs = 64.0f / s;
        half8 o0, o1;
#pragma unroll
        for (int j = 0; j < 8; j++) {
            o0[j] = (half_t)(v[j] * rs);
            o1[j] = (half_t)(v[8 + j] * rs);
        }
        half_t* orow = Qh + r * 1024 + lane * 16;
        *(half8*)(orow) = o0;
        *(half8*)(orow + 8) = o1;
    }
}

// ---------------------------------------------------------------------------
extern "C" void kernel_launch(void* const* d_in, const int* in_sizes, int n_in,
                              void* d_out, int out_size, void* d_ws, size_t ws_size,
                              hipStream_t stream)
{
    const float* x  = (const float*)d_in[0];
    const float* Wq = (const float*)d_in[1];
    const float* Wk = (const float*)d_in[2];
    const float* Wv = (const float*)d_in[3];
    const float* Wo = (const float*)d_in[4];
    const float* bo = (const float*)d_in[5];
    float* out = (float*)d_out;

    // Workspace (184 MiB):
    //   Xh 32 MiB (x as f16; dead after ctx GEMM inputs ready -> reused for P)
    //   KVreg 64 MiB: merged K|V'' logits [B][2048][4096]
    //     (K rows 0..1023, V'' = X*(Wv*Wo) rows 1024..2047, transposed layout)
    //   Q-logits live in d_out (64 MiB fp32 buffer, dead until final GEMM).
    char* w = (char*)d_ws;
    half_t* Xh  = (half_t*)w;                                  // 32 MiB
    half_t* P   = (half_t*)w;                                  // 32 MiB (aliases Xh)
    w += (size_t)R_ * D_ * 2;
    half_t* KVreg = (half_t*)w;                                // 64 MiB
    w += (size_t)B_ * 2048 * 4096 * 2;
    half_t* Qh  = (half_t*)w; w += (size_t)R_ * D_ * 2;        // 32 MiB (q * 64)
    half_t* Kt  = (half_t*)w; w += (size_t)R_ * D_ * 2;        // 32 MiB [B,D,N] (k * 64)
    half_t* Pw  = Kt;                                          // 8 MiB scratch (pre-softmax)
    half_t* Wt  = (half_t*)w; w += (size_t)4 * D_ * D_ * 2;    // 8 MiB (Wq^T|Wk^T|Wvo^T|Wo^T)
    half_t* ctxT = (half_t*)w; w += (size_t)B_ * D_ * D_ * 2;  // 8 MiB (64 * (K^T V'')^T)
    half_t* Wvh = (half_t*)w; w += (size_t)B_ * D_ * D_ * 2;   // 2 MiB used (Wv as f16)
    half_t* Qlog = (half_t*)out;                               // 32 MiB in d_out
    (void)ws_size; (void)in_sizes; (void)n_in; (void)out_size;

    const dim3 blk(256);
    const dim3 blkg(512);
    const long M1 = 1L << 20;

    // ---- all input conversions + weight transposes, one dispatch
    prep_fused<<<12800, blk, 0, stream>>>(x, Wq, Wk, Wv, Wo, Wt, Wvh, Xh);

    // ---- Wvo^T[o][k] = sum_e Wo^T[o,e] * Wv[k,e]  (fold Wo into the V path:
    // out = q*(ctx*Wo) = q*(K^T*(X*(Wv*Wo)))). Split-K=4 over e, f16 partials
    // into Pw (Kt region, free until softmax), reduce into Wt slot 2.
    gemmco<1, 2, 1><<<dim3(8, 4, 4), blkg, 0, stream>>>(Wt + 3 * M1, Wvh, Pw, nullptr,
        1024, 1024, 1024, 256, 0, 0, M1, 1.0f);
    ctx_reduce_h<<<512, blk, 0, stream>>>(Pw, Wt + 2 * M1);

    // ---- Q logits: Qlog[n,d] = Xh @ Wq (A big -> SWAP=1) -> d_out scratch
    gemmco<1, 0, 1><<<dim3(128, 4, 1), blkg, 0, stream>>>(Xh, Wt, Qlog, nullptr,
        1024, 1024, 1024, 1024, 0, 0, 0, 1.0f);

    // ---- merged K|V'' transposed: KVreg[b][m][n] = sum_k A[m,k] Xh[b][n,k]
    // with A rows = Wk^T (m 0..1023, K logits) | Wvo^T (m 1024..2047, V'').
    gemmco<1, 0, 0><<<dim3(16, 16, B_), blkg, 0, stream>>>(Wt + M1, Xh, KVreg, nullptr,
        1024, 1024, 4096, 1024, 0, (long)N_ * D_, (long)2048 * 4096, 1.0f);

    // ---- both softmaxes in one dispatch (seq part -> Kt, feature part -> Qh)
    softmax_fused<<<B_ * D_ + R_ / 4, blk, 0, stream>>>(KVreg, Kt, Qlog, Qh);

    // ---- ctxT[b][o][d] = sum_n v''[n,o] * (64 k[n,d])  (A = V''t slab,
    // Bt = Kt; both [.][n] layout). Split-K=4 over n, f16 partials in P
    // (Xh dead), reduce -> ctxT.
    gemmco<1, 2, 1><<<dim3(8, 4, 16), blkg, 0, stream>>>(KVreg + (long)1024 * 4096, Kt, P, nullptr,
        4096, 4096, 1024, N_ / 4,
        (long)2048 * 4096, (long)D_ * N_, M1, 1.0f);
    ctx_reduce_h<<<2048, blk, 0, stream>>>(P, ctxT);

    // ---- out[b][n][o] = (sum_d 64 q[n,d] * ctxT[b][o][d]) * 2^-25 + bo[o]
    // 2^-25 = (1/8 head scale) * (1/1024 D_OUT) * (1/64 q) * (1/64 k), all exact
    gemmco<2, 0, 1><<<dim3(32, 4, B_), blkg, 0, stream>>>(Qh, ctxT, out, bo,
        1024, 1024, 1024, 1024,
        (long)N_ * D_, M1, (long)N_ * D_,
        1.0f / 33554432.0f);
}